// Round 4
// baseline (969.465 us; speedup 1.0000x reference)
//
#include <hip/hip_runtime.h>
#include <cstddef>
#include <cstdint>

#define N_NODES 12288
#define D_IN    512
#define D_EMB   128
#define D_OUT   64
#define NEDGE   393216

typedef __attribute__((ext_vector_type(8))) short short8;
typedef __attribute__((ext_vector_type(4))) float f32x4;

__device__ __forceinline__ ushort f2bf(float f) {
  uint32_t u = __float_as_uint(f);
  u += 0x7fffu + ((u >> 16) & 1u);
  return (ushort)(u >> 16);
}
__device__ __forceinline__ float bf2f(ushort h) {
  return __uint_as_float((uint32_t)h << 16);
}

// ---------------------------------------------------------------------------
// generic fp32 -> bf16 hi/lo converter (n % 1024 == 0)
// ---------------------------------------------------------------------------
__global__ __launch_bounds__(256) void conv_hilo(const float* __restrict__ src,
    ushort* __restrict__ hi, ushort* __restrict__ lo)
{
  int idx = (blockIdx.x * 256 + threadIdx.x) * 4;
  float4 v = *(const float4*)(src + idx);
  const float* pv = &v.x;
  ushort4 h, l;
  ushort* ph = &h.x; ushort* pl = &l.x;
#pragma unroll
  for (int q = 0; q < 4; ++q) {
    ph[q] = f2bf(pv[q]);
    pl[q] = f2bf(pv[q] - bf2f(ph[q]));
  }
  *(ushort4*)(hi + idx) = h;
  *(ushort4*)(lo + idx) = l;
}

// ---------------------------------------------------------------------------
// x -> bf16 hi/lo (row-major) AND transposed bf16 hi/lo (for attribute GEMM)
// grid (192, 8): tile 64 rows(i) x 64 cols(c). Each thread handles 4 float4s
// (R3 bug: only 1 of 4 column groups was read -> 3/4 poison. Fixed.)
// ---------------------------------------------------------------------------
__global__ __launch_bounds__(256) void conv_x(const float* __restrict__ x,
    ushort* __restrict__ xhi, ushort* __restrict__ xlo,
    ushort* __restrict__ xThi, ushort* __restrict__ xTlo)
{
  __shared__ float t4[64][68];   // 68*4 = 272 B row stride (16B-aligned)
  int i0 = blockIdx.x * 64, c0 = blockIdx.y * 64;
  int ty = threadIdx.x >> 2;   // 0..63 row in tile
  int tx = threadIdx.x & 3;    // base float4 group
#pragma unroll
  for (int p = 0; p < 4; ++p) {
    int col = (tx + p * 4) * 4;            // 0,16,32,48 offsets + tx*4 -> all 64
    float4 v = *(const float4*)(x + (size_t)(i0 + ty) * D_IN + c0 + col);
    const float* pv = &v.x;
    ushort4 h, l;
    ushort* ph = &h.x; ushort* pl = &l.x;
#pragma unroll
    for (int q = 0; q < 4; ++q) {
      ph[q] = f2bf(pv[q]);
      pl[q] = f2bf(pv[q] - bf2f(ph[q]));
      t4[col + q][ty] = pv[q];
    }
    size_t o = (size_t)(i0 + ty) * D_IN + c0 + col;
    *(ushort4*)(xhi + o) = h;
    *(ushort4*)(xlo + o) = l;
  }
  __syncthreads();
  int cy = threadIdx.x >> 2;   // 0..63 c-row of transposed tile
  int cx = threadIdx.x & 3;    // 16-wide i group
#pragma unroll
  for (int g4 = 0; g4 < 4; ++g4) {
    float4 w = *(const float4*)&t4[cy][cx * 16 + g4 * 4];
    const float* pw = &w.x;
    ushort4 th, tl;
    ushort* pth = &th.x; ushort* ptl = &tl.x;
#pragma unroll
    for (int q = 0; q < 4; ++q) {
      pth[q] = f2bf(pw[q]);
      ptl[q] = f2bf(pw[q] - bf2f(pth[q]));
    }
    size_t ot = (size_t)(c0 + cy) * N_NODES + i0 + cx * 16 + g4 * 4;
    *(ushort4*)(xThi + ot) = th;
    *(ushort4*)(xTlo + ot) = tl;
  }
}

// ---------------------------------------------------------------------------
// CSR build
// ---------------------------------------------------------------------------
__global__ __launch_bounds__(256) void init_kernel(const int* __restrict__ ei,
    int* __restrict__ flag, int* __restrict__ deg)
{
  int idx = blockIdx.x * 256 + threadIdx.x;
  if (idx < N_NODES) deg[idx] = 0;
  if (idx == 0) {
    int ok = 1;
    for (int t = 0; t < 64; ++t) ok &= (ei[2 * t + 1] == 0);
    *flag = ok;  // 1 => data is int64, 0 => int32
  }
}

__global__ __launch_bounds__(256) void edge_deg(const int* __restrict__ ei,
    const int* __restrict__ flag, int* __restrict__ deg)
{
  int e = blockIdx.x * 256 + threadIdx.x;
  if (e >= NEDGE) return;
  int dst = (*flag) ? ei[2 * (NEDGE + e)] : ei[NEDGE + e];
  atomicAdd(&deg[dst], 1);
}

__global__ __launch_bounds__(256) void scan_deg(const int* __restrict__ deg,
    int* __restrict__ rp, int* __restrict__ cursor)
{
  __shared__ int sums[256];
  constexpr int C = N_NODES / 256;  // 48
  int t = threadIdx.x;
  int base = t * C;
  int local[C];
  int s = 0;
  for (int i = 0; i < C; ++i) { local[i] = deg[base + i]; s += local[i]; }
  sums[t] = s;
  __syncthreads();
  for (int off = 1; off < 256; off <<= 1) {
    int v = (t >= off) ? sums[t - off] : 0;
    __syncthreads();
    sums[t] += v;
    __syncthreads();
  }
  int prefix = (t == 0) ? 0 : sums[t - 1];
  for (int i = 0; i < C; ++i) {
    rp[base + i] = prefix;
    cursor[base + i] = prefix;
    prefix += local[i];
  }
  if (t == 255) rp[N_NODES] = prefix;
}

__global__ __launch_bounds__(256) void edge_scatter(const int* __restrict__ ei,
    const int* __restrict__ flag, int* __restrict__ cursor, int* __restrict__ csr)
{
  int e = blockIdx.x * 256 + threadIdx.x;
  if (e >= NEDGE) return;
  int is64 = *flag;
  int src = is64 ? ei[2 * e] : ei[e];
  int dst = is64 ? ei[2 * (NEDGE + e)] : ei[NEDGE + e];
  int p = atomicAdd(&cursor[dst], 1);
  csr[p] = src;
}

// ---------------------------------------------------------------------------
// Universal NT MFMA GEMM, 3-term bf16 hi/lo split (lo*lo dropped).
// Wave tile 64x64 (4x4 of 16x16x32); block = WY x WX waves.
// Direct-global fragment loads (operands are L2/L3-resident).
// grid.z = split-K chunks (K = chunk length, part_stride = output stride).
// MODE 0: fp32 out. MODE 1: +bias, relu, bf16 hi/lo out.
// Layouts (m89/m91, validated by round-2 sig kernel):
//   A/B frag: [m = lane&15][k = (lane>>4)*8 + j]
//   C/D:      col = lane&15, row = (lane>>4)*4 + reg
// ---------------------------------------------------------------------------
template<int WY, int WX, int MODE>
__global__ __launch_bounds__(256) void mfma_nt(
    const ushort* __restrict__ Ahi, const ushort* __restrict__ Alo,
    const ushort* __restrict__ Bhi, const ushort* __restrict__ Blo,
    const float* __restrict__ bias,
    float* __restrict__ Cf, ushort* __restrict__ Chi, ushort* __restrict__ Clo,
    int lda, int ldb, int K, int ldc, size_t part_stride)
{
  int lane = threadIdx.x & 63;
  int wave = threadIdx.x >> 6;
  int wy = wave / WX, wx = wave % WX;
  int i0 = blockIdx.x * (64 * WY) + wy * 64;
  int j0 = blockIdx.y * (64 * WX) + wx * 64;
  int kbase = blockIdx.z * K;
  float* Cout = Cf + (size_t)blockIdx.z * part_stride;
  int lm = lane & 15, lk = lane >> 4;
  f32x4 acc[4][4];
#pragma unroll
  for (int r = 0; r < 4; ++r)
#pragma unroll
    for (int c = 0; c < 4; ++c) acc[r][c] = (f32x4){0.f, 0.f, 0.f, 0.f};

  for (int k0 = 0; k0 < K; k0 += 32) {
    int kk = kbase + k0 + lk * 8;
    short8 Ah[4], Al[4], Bh[4], Bl[4];
#pragma unroll
    for (int t = 0; t < 4; ++t) {
      size_t ra = (size_t)(i0 + t * 16 + lm) * lda + kk;
      size_t rb = (size_t)(j0 + t * 16 + lm) * ldb + kk;
      Ah[t] = *(const short8*)(Ahi + ra);
      Al[t] = *(const short8*)(Alo + ra);
      Bh[t] = *(const short8*)(Bhi + rb);
      Bl[t] = *(const short8*)(Blo + rb);
    }
#pragma unroll
    for (int r = 0; r < 4; ++r)
#pragma unroll
      for (int c = 0; c < 4; ++c) {
        acc[r][c] = __builtin_amdgcn_mfma_f32_16x16x32_bf16(Ah[r], Bh[c], acc[r][c], 0, 0, 0);
        acc[r][c] = __builtin_amdgcn_mfma_f32_16x16x32_bf16(Ah[r], Bl[c], acc[r][c], 0, 0, 0);
        acc[r][c] = __builtin_amdgcn_mfma_f32_16x16x32_bf16(Al[r], Bh[c], acc[r][c], 0, 0, 0);
      }
  }
#pragma unroll
  for (int r = 0; r < 4; ++r)
#pragma unroll
    for (int c = 0; c < 4; ++c) {
      int col = j0 + c * 16 + lm;
#pragma unroll
      for (int q = 0; q < 4; ++q) {
        int row = i0 + r * 16 + lk * 4 + q;
        float v = acc[r][c][q];
        if (MODE == 0) {
          Cout[(size_t)row * ldc + col] = v;
        } else {
          v += bias[col];
          v = fmaxf(v, 0.f);
          ushort hb = f2bf(v);
          Chi[(size_t)row * ldc + col] = hb;
          Clo[(size_t)row * ldc + col] = f2bf(v - bf2f(hb));
        }
      }
    }
}

// ---------------------------------------------------------------------------
// small fp32 NT GEMM (kept for xa: 512x64x128)
// ---------------------------------------------------------------------------
template<int ACT>
__global__ __launch_bounds__(256) void gemm_nt64(const float* __restrict__ A,
    const float* __restrict__ B, const float* __restrict__ bias,
    float* __restrict__ C, int M, int N, int K, int ldc)
{
  __shared__ float As[32][64];
  __shared__ float Bs[32][64];
  int m0 = blockIdx.x * 64, n0 = blockIdx.y * 64;
  int tid = threadIdx.x;
  int tx = tid & 15, ty = tid >> 4;
  float acc[4][4] = {};
  for (int k0 = 0; k0 < K; k0 += 32) {
#pragma unroll
    for (int p = 0; p < 2; ++p) {
      int idx = tid + p * 256;
      int row = idx >> 3;
      int kq  = idx & 7;
      float4 va = *(const float4*)(A + (size_t)(m0 + row) * K + k0 + kq * 4);
      As[kq*4+0][row] = va.x; As[kq*4+1][row] = va.y;
      As[kq*4+2][row] = va.z; As[kq*4+3][row] = va.w;
      float4 vb = *(const float4*)(B + (size_t)(n0 + row) * K + k0 + kq * 4);
      Bs[kq*4+0][row] = vb.x; Bs[kq*4+1][row] = vb.y;
      Bs[kq*4+2][row] = vb.z; Bs[kq*4+3][row] = vb.w;
    }
    __syncthreads();
#pragma unroll
    for (int k = 0; k < 32; ++k) {
      float a[4], b[4];
      *(float4*)a = *(const float4*)&As[k][ty * 4];
      *(float4*)b = *(const float4*)&Bs[k][tx * 4];
#pragma unroll
      for (int r = 0; r < 4; ++r)
#pragma unroll
        for (int c = 0; c < 4; ++c)
          acc[r][c] = fmaf(a[r], b[c], acc[r][c]);
    }
    __syncthreads();
  }
#pragma unroll
  for (int r = 0; r < 4; ++r) {
    int m = m0 + ty * 4 + r;
    float4 o;
    float* po = &o.x;
#pragma unroll
    for (int c = 0; c < 4; ++c) {
      float v = acc[r][c];
      if (bias) v += bias[n0 + tx * 4 + c];
      if (ACT) v = fmaxf(v, 0.f);
      po[c] = v;
    }
    *(float4*)(C + (size_t)m * ldc + n0 + tx * 4) = o;
  }
}

// per-node attention scores
__global__ __launch_bounds__(256) void scores_kernel(const float* __restrict__ g,
    const float* __restrict__ a_src, const float* __restrict__ a_dst,
    float* __restrict__ sc_s, float* __restrict__ sc_d)
{
  int lane = threadIdx.x & 63;
  int i = blockIdx.x * 4 + (threadIdx.x >> 6);
  float gv = g[(size_t)i * 64 + lane];
  float vs = gv * a_src[lane];
  float vd = gv * a_dst[lane];
#pragma unroll
  for (int off = 32; off; off >>= 1) {
    vs += __shfl_xor(vs, off);
    vd += __shfl_xor(vd, off);
  }
  if (lane == 0) { sc_s[i] = vs; sc_d[i] = vd; }
}

// one wave per destination node; emits bf16 hi/lo h only
__global__ __launch_bounds__(256) void gat_kernel(const int* __restrict__ rp,
    const int* __restrict__ csr, const float* __restrict__ sc_s,
    const float* __restrict__ sc_d, const float* __restrict__ g,
    const float* __restrict__ b_g,
    ushort* __restrict__ hhi, ushort* __restrict__ hlo)
{
  int lane = threadIdx.x & 63;
  int i = blockIdx.x * 4 + (threadIdx.x >> 6);
  int beg = rp[i], end = rp[i + 1];
  int deg = end - beg;
  float scd = sc_d[i];
  float mymax = -3.4e38f;
  for (int j = lane; j <= deg; j += 64) {
    int s = (j < deg) ? csr[beg + j] : i;
    float e = sc_s[s] + scd;
    e = (e > 0.f) ? e : 0.2f * e;
    mymax = fmaxf(mymax, e);
  }
#pragma unroll
  for (int off = 32; off; off >>= 1) mymax = fmaxf(mymax, __shfl_xor(mymax, off));
  float sum = 0.f;
  for (int j = lane; j <= deg; j += 64) {
    int s = (j < deg) ? csr[beg + j] : i;
    float e = sc_s[s] + scd;
    e = (e > 0.f) ? e : 0.2f * e;
    sum += __expf(e - mymax);
  }
#pragma unroll
  for (int off = 32; off; off >>= 1) sum += __shfl_xor(sum, off);
  float inv = 1.f / sum;
  float acc = 0.f;
  for (int j = 0; j <= deg; ++j) {
    int s = (j < deg) ? csr[beg + j] : i;
    float e = sc_s[s] + scd;
    e = (e > 0.f) ? e : 0.2f * e;
    float w = __expf(e - mymax) * inv;
    acc = fmaf(w, g[(size_t)s * 64 + lane], acc);
  }
  float val = acc + b_g[lane];
  size_t o = (size_t)i * 64 + lane;
  ushort hi = f2bf(val);
  hhi[o] = hi;
  hlo[o] = f2bf(val - bf2f(hi));
}

// reduce 32 split-K partials, add bias, relu
__global__ __launch_bounds__(256) void xt_ep(const float* __restrict__ part,
    const float* __restrict__ b_a1, float* __restrict__ xt)
{
  int idx = blockIdx.x * 256 + threadIdx.x;  // 65536
  float v = b_a1[idx & 127];
#pragma unroll 8
  for (int c = 0; c < 32; ++c) v += part[(size_t)c * (D_IN * D_EMB) + idx];
  xt[idx] = fmaxf(v, 0.f);
}

// ---------------------------------------------------------------------------
// s_ = sigmoid(h @ h^T), bf16 MFMA 3-term, 128x128 per block, no LDS
// ---------------------------------------------------------------------------
__global__ __launch_bounds__(256) void sig_hht_mfma(const ushort* __restrict__ hhi,
    const ushort* __restrict__ hlo, float* __restrict__ out)
{
  int lane = threadIdx.x & 63;
  int wave = threadIdx.x >> 6;
  int i0 = blockIdx.x * 128 + (wave >> 1) * 64;
  int j0 = blockIdx.y * 128 + (wave & 1) * 64;
  int lm = lane & 15, lk = lane >> 4;
  f32x4 acc[4][4];
#pragma unroll
  for (int r = 0; r < 4; ++r)
#pragma unroll
    for (int c = 0; c < 4; ++c) acc[r][c] = (f32x4){0.f, 0.f, 0.f, 0.f};
#pragma unroll
  for (int ks = 0; ks < 2; ++ks) {
    short8 Ah[4], Al[4], Bh[4], Bl[4];
#pragma unroll
    for (int t = 0; t < 4; ++t) {
      size_t ra = (size_t)(i0 + t * 16 + lm) * 64 + ks * 32 + lk * 8;
      size_t rb = (size_t)(j0 + t * 16 + lm) * 64 + ks * 32 + lk * 8;
      Ah[t] = *(const short8*)(hhi + ra);
      Al[t] = *(const short8*)(hlo + ra);
      Bh[t] = *(const short8*)(hhi + rb);
      Bl[t] = *(const short8*)(hlo + rb);
    }
#pragma unroll
    for (int r = 0; r < 4; ++r)
#pragma unroll
      for (int c = 0; c < 4; ++c) {
        acc[r][c] = __builtin_amdgcn_mfma_f32_16x16x32_bf16(Ah[r], Bh[c], acc[r][c], 0, 0, 0);
        acc[r][c] = __builtin_amdgcn_mfma_f32_16x16x32_bf16(Ah[r], Bl[c], acc[r][c], 0, 0, 0);
        acc[r][c] = __builtin_amdgcn_mfma_f32_16x16x32_bf16(Al[r], Bh[c], acc[r][c], 0, 0, 0);
      }
  }
#pragma unroll
  for (int r = 0; r < 4; ++r)
#pragma unroll
    for (int c = 0; c < 4; ++c) {
#pragma unroll
      for (int q = 0; q < 4; ++q) {
        float v = acc[r][c][q];
        float ex = __expf(-v);
        float s = 1.f / (1.f + ex);
        out[(size_t)(i0 + r * 16 + lk * 4 + q) * N_NODES + (j0 + c * 16 + lm)] = s;
      }
    }
}

// ---------------------------------------------------------------------------
extern "C" void kernel_launch(void* const* d_in, const int* in_sizes, int n_in,
                              void* d_out, int out_size, void* d_ws, size_t ws_size,
                              hipStream_t stream)
{
  const float* x     = (const float*)d_in[0];
  const float* W_s1  = (const float*)d_in[1];
  const float* b_s1  = (const float*)d_in[2];
  const float* W_g   = (const float*)d_in[3];
  const float* a_src = (const float*)d_in[4];
  const float* a_dst = (const float*)d_in[5];
  const float* b_g   = (const float*)d_in[6];
  const float* W_a1  = (const float*)d_in[7];
  const float* b_a1  = (const float*)d_in[8];
  const float* W_a2  = (const float*)d_in[9];
  const float* b_a2  = (const float*)d_in[10];
  const int*   ei    = (const int*)d_in[11];

  // ---- workspace carve-up (floats, then ints, then ushorts; all 16B-aligned)
  float* ws   = (float*)d_ws;
  float* g    = ws;                              // 786432
  float* sc_s = g + (size_t)N_NODES * D_OUT;     // 12288
  float* sc_d = sc_s + N_NODES;                  // 12288
  float* part = sc_d + N_NODES;                  // 32*65536 = 2097152
  float* xt   = part + (size_t)32 * D_IN * D_EMB;// 65536
  float* xa   = xt + D_IN * D_EMB;               // 32768
  int* ip     = (int*)(xa + D_IN * D_OUT);
  int* flag   = ip;                              // 64
  int* deg    = ip + 64;                         // 12288
  int* rp     = deg + N_NODES;                   // 12352 (12289 used)
  int* cursor = rp + 12352;                      // 12288
  int* csr    = cursor + N_NODES;                // 393216
  ushort* up  = (ushort*)(csr + NEDGE);
  ushort* xhi  = up;                         up += (size_t)N_NODES * D_IN;
  ushort* xlo  = up;                         up += (size_t)N_NODES * D_IN;
  ushort* xThi = up;                         up += (size_t)N_NODES * D_IN;
  ushort* xTlo = up;                         up += (size_t)N_NODES * D_IN;
  ushort* x1hi = up;                         up += (size_t)N_NODES * D_EMB;
  ushort* x1lo = up;                         up += (size_t)N_NODES * D_EMB;
  ushort* Ws1hi = up;                        up += (size_t)D_EMB * D_IN;
  ushort* Ws1lo = up;                        up += (size_t)D_EMB * D_IN;
  ushort* Wghi = up;                         up += (size_t)D_OUT * D_EMB;
  ushort* Wglo = up;                         up += (size_t)D_OUT * D_EMB;
  ushort* Wa1hi = up;                        up += (size_t)D_EMB * N_NODES;
  ushort* Wa1lo = up;                        up += (size_t)D_EMB * N_NODES;
  ushort* hhi = up;                          up += (size_t)N_NODES * D_OUT;
  ushort* hlo = up;                          up += (size_t)N_NODES * D_OUT;
  ushort* xahi = up;                         up += (size_t)D_IN * D_OUT;
  ushort* xalo = up;                         up += (size_t)D_IN * D_OUT;

  float* out_x = (float*)d_out;                       // 12288*512
  float* out_s = out_x + (size_t)N_NODES * D_IN;      // 12288*12288

  // ---- input conversions
  conv_x<<<dim3(192, 8), 256, 0, stream>>>(x, xhi, xlo, xThi, xTlo);
  conv_hilo<<<(D_EMB * D_IN) / 1024, 256, 0, stream>>>(W_s1, Ws1hi, Ws1lo);
  conv_hilo<<<(D_OUT * D_EMB) / 1024, 256, 0, stream>>>(W_g, Wghi, Wglo);
  conv_hilo<<<((size_t)D_EMB * N_NODES) / 1024, 256, 0, stream>>>(W_a1, Wa1hi, Wa1lo);

  // ---- CSR build
  init_kernel<<<48, 256, 0, stream>>>(ei, flag, deg);
  edge_deg<<<NEDGE / 256, 256, 0, stream>>>(ei, flag, deg);
  scan_deg<<<1, 256, 0, stream>>>(deg, rp, cursor);
  edge_scatter<<<NEDGE / 256, 256, 0, stream>>>(ei, flag, cursor, csr);

  // ---- structure branch: x1 = relu(x@W_s1^T + b) -> bf16 hi/lo
  mfma_nt<2, 2, 1><<<dim3(96, 1, 1), 256, 0, stream>>>(
      xhi, xlo, Ws1hi, Ws1lo, b_s1, nullptr, x1hi, x1lo,
      D_IN, D_IN, D_IN, D_EMB, 0);
  // g = x1 @ W_g^T (fp32 out)
  mfma_nt<4, 1, 0><<<dim3(48, 1, 1), 256, 0, stream>>>(
      x1hi, x1lo, Wghi, Wglo, nullptr, g, nullptr, nullptr,
      D_EMB, D_EMB, D_EMB, D_OUT, 0);
  scores_kernel<<<N_NODES / 4, 256, 0, stream>>>(g, a_src, a_dst, sc_s, sc_d);
  gat_kernel<<<N_NODES / 4, 256, 0, stream>>>(rp, csr, sc_s, sc_d, g, b_g,
                                              hhi, hlo);

  // ---- attribute branch: xt^pre[c][j] = sum_i xT[c][i] * W_a1[j][i], split-K
  mfma_nt<2, 2, 0><<<dim3(4, 1, 32), 256, 0, stream>>>(
      xThi, xTlo, Wa1hi, Wa1lo, nullptr, part, nullptr, nullptr,
      N_NODES, N_NODES, 384, D_EMB, (size_t)D_IN * D_EMB);
  xt_ep<<<D_IN * D_EMB / 256, 256, 0, stream>>>(part, b_a1, xt);
  gemm_nt64<0><<<dim3(8, 1), 256, 0, stream>>>(xt, W_a2, b_a2, xa,
                                               D_IN, D_OUT, D_EMB, D_OUT);
  conv_hilo<<<(D_IN * D_OUT) / 1024, 256, 0, stream>>>(xa, xahi, xalo);

  // ---- outputs
  mfma_nt<2, 2, 0><<<dim3(96, 4, 1), 256, 0, stream>>>(
      hhi, hlo, xahi, xalo, nullptr, out_x, nullptr, nullptr,
      D_OUT, D_OUT, D_OUT, D_IN, 0);
  sig_hht_mfma<<<dim3(96, 96), 256, 0, stream>>>(hhi, hlo, out_s);
}

// Round 5
// 914.647 us; speedup vs baseline: 1.0599x; 1.0599x over previous
//
#include <hip/hip_runtime.h>
#include <cstddef>
#include <cstdint>

#define N_NODES 12288
#define D_IN    512
#define D_EMB   128
#define D_OUT   64
#define NEDGE   393216

typedef __attribute__((ext_vector_type(8))) short short8;
typedef __attribute__((ext_vector_type(4))) float f32x4;

__device__ __forceinline__ ushort f2bf(float f) {
  uint32_t u = __float_as_uint(f);
  u += 0x7fffu + ((u >> 16) & 1u);
  return (ushort)(u >> 16);
}
__device__ __forceinline__ float bf2f(ushort h) {
  return __uint_as_float((uint32_t)h << 16);
}

// ---------------------------------------------------------------------------
// streaming fp32 -> bf16 hi/lo (n % 1024 == 0)
// ---------------------------------------------------------------------------
__global__ __launch_bounds__(256) void conv_hilo(const float* __restrict__ src,
    ushort* __restrict__ hi, ushort* __restrict__ lo)
{
  int idx = (blockIdx.x * 256 + threadIdx.x) * 4;
  float4 v = *(const float4*)(src + idx);
  const float* pv = &v.x;
  ushort4 h, l;
  ushort* ph = &h.x; ushort* pl = &l.x;
#pragma unroll
  for (int q = 0; q < 4; ++q) {
    ph[q] = f2bf(pv[q]);
    pl[q] = f2bf(pv[q] - bf2f(ph[q]));
  }
  *(ushort4*)(hi + idx) = h;
  *(ushort4*)(lo + idx) = l;
}

// merged W_s1 (65536) + W_g (8192) conversion: blocks [0,64) and [64,72)
__global__ __launch_bounds__(256) void conv_w(const float* __restrict__ Ws1,
    const float* __restrict__ Wg, ushort* __restrict__ s1h, ushort* __restrict__ s1l,
    ushort* __restrict__ wgh, ushort* __restrict__ wgl)
{
  int b = blockIdx.x;
  const float* src; ushort* hi; ushort* lo; int idx;
  if (b < 64) { src = Ws1; hi = s1h; lo = s1l; idx = (b * 256 + threadIdx.x) * 4; }
  else        { src = Wg;  hi = wgh; lo = wgl; idx = ((b - 64) * 256 + threadIdx.x) * 4; }
  float4 v = *(const float4*)(src + idx);
  const float* pv = &v.x;
  ushort4 h, l;
  ushort* ph = &h.x; ushort* pl = &l.x;
#pragma unroll
  for (int q = 0; q < 4; ++q) {
    ph[q] = f2bf(pv[q]);
    pl[q] = f2bf(pv[q] - bf2f(ph[q]));
  }
  *(ushort4*)(hi + idx) = h;
  *(ushort4*)(lo + idx) = l;
}

// ---------------------------------------------------------------------------
// CSR build
// ---------------------------------------------------------------------------
__global__ __launch_bounds__(256) void init_kernel(const int* __restrict__ ei,
    int* __restrict__ flag, int* __restrict__ deg)
{
  int idx = blockIdx.x * 256 + threadIdx.x;
  if (idx < N_NODES) deg[idx] = 0;
  if (idx == 0) {
    int ok = 1;
    for (int t = 0; t < 64; ++t) ok &= (ei[2 * t + 1] == 0);
    *flag = ok;  // 1 => data is int64, 0 => int32
  }
}

__global__ __launch_bounds__(256) void edge_deg(const int* __restrict__ ei,
    const int* __restrict__ flag, int* __restrict__ deg)
{
  int e = blockIdx.x * 256 + threadIdx.x;
  if (e >= NEDGE) return;
  int dst = (*flag) ? ei[2 * (NEDGE + e)] : ei[NEDGE + e];
  atomicAdd(&deg[dst], 1);
}

__global__ __launch_bounds__(256) void scan_deg(const int* __restrict__ deg,
    int* __restrict__ rp, int* __restrict__ cursor)
{
  __shared__ int sums[256];
  constexpr int C = N_NODES / 256;  // 48
  int t = threadIdx.x;
  int base = t * C;
  int local[C];
  int s = 0;
  for (int i = 0; i < C; ++i) { local[i] = deg[base + i]; s += local[i]; }
  sums[t] = s;
  __syncthreads();
  for (int off = 1; off < 256; off <<= 1) {
    int v = (t >= off) ? sums[t - off] : 0;
    __syncthreads();
    sums[t] += v;
    __syncthreads();
  }
  int prefix = (t == 0) ? 0 : sums[t - 1];
  for (int i = 0; i < C; ++i) {
    rp[base + i] = prefix;
    cursor[base + i] = prefix;
    prefix += local[i];
  }
  if (t == 255) rp[N_NODES] = prefix;
}

__global__ __launch_bounds__(256) void edge_scatter(const int* __restrict__ ei,
    const int* __restrict__ flag, int* __restrict__ cursor, int* __restrict__ csr)
{
  int e = blockIdx.x * 256 + threadIdx.x;
  if (e >= NEDGE) return;
  int is64 = *flag;
  int src = is64 ? ei[2 * e] : ei[e];
  int dst = is64 ? ei[2 * (NEDGE + e)] : ei[NEDGE + e];
  int p = atomicAdd(&cursor[dst], 1);
  csr[p] = src;
}

// ---------------------------------------------------------------------------
// Single-wave NT MFMA GEMM, 3-term bf16 hi/lo split (lo*lo dropped).
// One 64x64 wave tile per 64-thread block; grid (M/64, N/64).
// MODE 0: fp32 out. MODE 1: +bias, relu, bf16 hi/lo out.
// Layouts (m89/m91, validated R2/R4):
//   A/B frag: [m = lane&15][k = (lane>>4)*8 + j]
//   C/D:      col = lane&15, row = (lane>>4)*4 + reg
// ---------------------------------------------------------------------------
template<int MODE>
__global__ __launch_bounds__(64) void mfma_nt1(
    const ushort* __restrict__ Ahi, const ushort* __restrict__ Alo,
    const ushort* __restrict__ Bhi, const ushort* __restrict__ Blo,
    const float* __restrict__ bias,
    float* __restrict__ Cf, ushort* __restrict__ Chi, ushort* __restrict__ Clo,
    int lda, int ldb, int K, int ldc)
{
  int lane = threadIdx.x;
  int i0 = blockIdx.x * 64;
  int j0 = blockIdx.y * 64;
  int lm = lane & 15, lk = lane >> 4;
  f32x4 acc[4][4];
#pragma unroll
  for (int r = 0; r < 4; ++r)
#pragma unroll
    for (int c = 0; c < 4; ++c) acc[r][c] = (f32x4){0.f, 0.f, 0.f, 0.f};

  for (int k0 = 0; k0 < K; k0 += 32) {
    int kk = k0 + lk * 8;
    short8 Ah[4], Al[4], Bh[4], Bl[4];
#pragma unroll
    for (int t = 0; t < 4; ++t) {
      size_t ra = (size_t)(i0 + t * 16 + lm) * lda + kk;
      size_t rb = (size_t)(j0 + t * 16 + lm) * ldb + kk;
      Ah[t] = *(const short8*)(Ahi + ra);
      Al[t] = *(const short8*)(Alo + ra);
      Bh[t] = *(const short8*)(Bhi + rb);
      Bl[t] = *(const short8*)(Blo + rb);
    }
#pragma unroll
    for (int r = 0; r < 4; ++r)
#pragma unroll
      for (int c = 0; c < 4; ++c) {
        acc[r][c] = __builtin_amdgcn_mfma_f32_16x16x32_bf16(Ah[r], Bh[c], acc[r][c], 0, 0, 0);
        acc[r][c] = __builtin_amdgcn_mfma_f32_16x16x32_bf16(Ah[r], Bl[c], acc[r][c], 0, 0, 0);
        acc[r][c] = __builtin_amdgcn_mfma_f32_16x16x32_bf16(Al[r], Bh[c], acc[r][c], 0, 0, 0);
      }
  }
#pragma unroll
  for (int r = 0; r < 4; ++r)
#pragma unroll
    for (int c = 0; c < 4; ++c) {
      int col = j0 + c * 16 + lm;
#pragma unroll
      for (int q = 0; q < 4; ++q) {
        int row = i0 + r * 16 + lk * 4 + q;
        float v = acc[r][c][q];
        if (MODE == 0) {
          Cf[(size_t)row * ldc + col] = v;
        } else {
          v += bias[col];
          v = fmaxf(v, 0.f);
          ushort hb = f2bf(v);
          Chi[(size_t)row * ldc + col] = hb;
          Clo[(size_t)row * ldc + col] = f2bf(v - bf2f(hb));
        }
      }
    }
}

// ---------------------------------------------------------------------------
// small fp32 NT GEMM (xa: 512x64x128)
// ---------------------------------------------------------------------------
template<int ACT>
__global__ __launch_bounds__(256) void gemm_nt64(const float* __restrict__ A,
    const float* __restrict__ B, const float* __restrict__ bias,
    float* __restrict__ C, int M, int N, int K, int ldc)
{
  __shared__ float As[32][64];
  __shared__ float Bs[32][64];
  int m0 = blockIdx.x * 64, n0 = blockIdx.y * 64;
  int tid = threadIdx.x;
  int tx = tid & 15, ty = tid >> 4;
  float acc[4][4] = {};
  for (int k0 = 0; k0 < K; k0 += 32) {
#pragma unroll
    for (int p = 0; p < 2; ++p) {
      int idx = tid + p * 256;
      int row = idx >> 3;
      int kq  = idx & 7;
      float4 va = *(const float4*)(A + (size_t)(m0 + row) * K + k0 + kq * 4);
      As[kq*4+0][row] = va.x; As[kq*4+1][row] = va.y;
      As[kq*4+2][row] = va.z; As[kq*4+3][row] = va.w;
      float4 vb = *(const float4*)(B + (size_t)(n0 + row) * K + k0 + kq * 4);
      Bs[kq*4+0][row] = vb.x; Bs[kq*4+1][row] = vb.y;
      Bs[kq*4+2][row] = vb.z; Bs[kq*4+3][row] = vb.w;
    }
    __syncthreads();
#pragma unroll
    for (int k = 0; k < 32; ++k) {
      float a[4], b[4];
      *(float4*)a = *(const float4*)&As[k][ty * 4];
      *(float4*)b = *(const float4*)&Bs[k][tx * 4];
#pragma unroll
      for (int r = 0; r < 4; ++r)
#pragma unroll
        for (int c = 0; c < 4; ++c)
          acc[r][c] = fmaf(a[r], b[c], acc[r][c]);
    }
    __syncthreads();
  }
#pragma unroll
  for (int r = 0; r < 4; ++r) {
    int m = m0 + ty * 4 + r;
    float4 o;
    float* po = &o.x;
#pragma unroll
    for (int c = 0; c < 4; ++c) {
      float v = acc[r][c];
      if (bias) v += bias[n0 + tx * 4 + c];
      if (ACT) v = fmaxf(v, 0.f);
      po[c] = v;
    }
    *(float4*)(C + (size_t)m * ldc + n0 + tx * 4) = o;
  }
}

// per-node attention scores
__global__ __launch_bounds__(256) void scores_kernel(const float* __restrict__ g,
    const float* __restrict__ a_src, const float* __restrict__ a_dst,
    float* __restrict__ sc_s, float* __restrict__ sc_d)
{
  int lane = threadIdx.x & 63;
  int i = blockIdx.x * 4 + (threadIdx.x >> 6);
  float gv = g[(size_t)i * 64 + lane];
  float vs = gv * a_src[lane];
  float vd = gv * a_dst[lane];
#pragma unroll
  for (int off = 32; off; off >>= 1) {
    vs += __shfl_xor(vs, off);
    vd += __shfl_xor(vd, off);
  }
  if (lane == 0) { sc_s[i] = vs; sc_d[i] = vd; }
}

// one wave per destination node; softmax weights cached in per-wave LDS
#define WCAP 192
__global__ __launch_bounds__(256) void gat_kernel(const int* __restrict__ rp,
    const int* __restrict__ csr, const float* __restrict__ sc_s,
    const float* __restrict__ sc_d, const float* __restrict__ g,
    const float* __restrict__ b_g,
    ushort* __restrict__ hhi, ushort* __restrict__ hlo)
{
  __shared__ float wbuf[4][WCAP];
  __shared__ int   sbuf[4][WCAP];
  int lane = threadIdx.x & 63;
  int w = threadIdx.x >> 6;
  int i = blockIdx.x * 4 + w;
  int beg = rp[i], end = rp[i + 1];
  int deg = end - beg;
  float scd = sc_d[i];
  float mymax = -3.4e38f;
  for (int j = lane; j <= deg; j += 64) {
    int s = (j < deg) ? csr[beg + j] : i;
    float e = sc_s[s] + scd;
    e = (e > 0.f) ? e : 0.2f * e;
    mymax = fmaxf(mymax, e);
    if (j < WCAP) sbuf[w][j] = s;
  }
#pragma unroll
  for (int off = 32; off; off >>= 1) mymax = fmaxf(mymax, __shfl_xor(mymax, off));
  float sum = 0.f;
  for (int j = lane; j <= deg; j += 64) {
    int s = (j < WCAP) ? sbuf[w][j] : ((j < deg) ? csr[beg + j] : i);
    float e = sc_s[s] + scd;
    e = (e > 0.f) ? e : 0.2f * e;
    float ex = __expf(e - mymax);
    sum += ex;
    if (j < WCAP) wbuf[w][j] = ex;
  }
#pragma unroll
  for (int off = 32; off; off >>= 1) sum += __shfl_xor(sum, off);
  float inv = 1.f / sum;
  float acc = 0.f;   // lane == feature
  for (int j = 0; j <= deg; ++j) {
    int s; float ex;
    if (j < WCAP) { s = sbuf[w][j]; ex = wbuf[w][j]; }
    else {
      s = (j < deg) ? csr[beg + j] : i;
      float e = sc_s[s] + scd;
      e = (e > 0.f) ? e : 0.2f * e;
      ex = __expf(e - mymax);
    }
    acc = fmaf(ex * inv, g[(size_t)s * 64 + lane], acc);
  }
  float val = acc + b_g[lane];
  size_t o = (size_t)i * 64 + lane;
  ushort hi = f2bf(val);
  hhi[o] = hi;
  hlo[o] = f2bf(val - bf2f(hi));
}

// ---------------------------------------------------------------------------
// xt pre-activation partials (R2 config): part[chunk][c][j] over 192-row chunks
// grid (8 c-tiles, 64 chunks), 256 thr, thread tile 4c x 8j. No atomics.
// ---------------------------------------------------------------------------
__global__ __launch_bounds__(256) void xt_splitk(const float* __restrict__ x,
    const float* __restrict__ Wa1, float* __restrict__ part)
{
  __shared__ float Xs[32][64];    // [i][c]
  __shared__ float Ws[32][128];   // [i][j]
  int c0 = blockIdx.x * 64;
  int i0 = blockIdx.y * 192;
  float* pout = part + (size_t)blockIdx.y * (D_IN * D_EMB);
  int tid = threadIdx.x;
  int txc = tid & 15, txj = tid >> 4;
  float acc[4][8] = {};
  for (int ib = 0; ib < 192; ib += 32) {
#pragma unroll
    for (int p = 0; p < 2; ++p) {    // Xs: 32x64 = 512 float4
      int idx = tid + p * 256;
      int row = idx >> 4, q = idx & 15;
      *(float4*)&Xs[row][q * 4] =
          *(const float4*)(x + (size_t)(i0 + ib + row) * D_IN + c0 + q * 4);
    }
#pragma unroll
    for (int p = 0; p < 4; ++p) {    // Ws: 128 rows x 8 float4 (transposed store)
      int idx = tid + p * 256;
      int j = idx >> 3, q = idx & 7;
      float4 v = *(const float4*)(Wa1 + (size_t)j * N_NODES + i0 + ib + q * 4);
      Ws[q*4+0][j] = v.x; Ws[q*4+1][j] = v.y;
      Ws[q*4+2][j] = v.z; Ws[q*4+3][j] = v.w;
    }
    __syncthreads();
#pragma unroll
    for (int ii = 0; ii < 32; ++ii) {
      float a[4], b[8];
      *(float4*)a = *(const float4*)&Xs[ii][txc * 4];
      *(float4*)&b[0] = *(const float4*)&Ws[ii][txj * 8];
      *(float4*)&b[4] = *(const float4*)&Ws[ii][txj * 8 + 4];
#pragma unroll
      for (int r = 0; r < 4; ++r)
#pragma unroll
        for (int c = 0; c < 8; ++c)
          acc[r][c] = fmaf(a[r], b[c], acc[r][c]);
    }
    __syncthreads();
  }
#pragma unroll
  for (int r = 0; r < 4; ++r) {
    float4 o0, o1;
    o0.x = acc[r][0]; o0.y = acc[r][1]; o0.z = acc[r][2]; o0.w = acc[r][3];
    o1.x = acc[r][4]; o1.y = acc[r][5]; o1.z = acc[r][6]; o1.w = acc[r][7];
    size_t off = (size_t)(c0 + txc * 4 + r) * D_EMB + txj * 8;
    *(float4*)&pout[off] = o0;
    *(float4*)&pout[off + 4] = o1;
  }
}

// reduce 64 partial chunks, add bias, relu
__global__ __launch_bounds__(256) void xt_ep(const float* __restrict__ part,
    const float* __restrict__ b_a1, float* __restrict__ xt)
{
  int idx = blockIdx.x * 256 + threadIdx.x;  // 65536
  float v = b_a1[idx & 127];
#pragma unroll 8
  for (int c = 0; c < 64; ++c) v += part[(size_t)c * (D_IN * D_EMB) + idx];
  xt[idx] = fmaxf(v, 0.f);
}

// ---------------------------------------------------------------------------
// s_ = sigmoid(h @ h^T), bf16 MFMA 3-term, 128x128 per block, no LDS
// ---------------------------------------------------------------------------
__global__ __launch_bounds__(256) void sig_hht_mfma(const ushort* __restrict__ hhi,
    const ushort* __restrict__ hlo, float* __restrict__ out)
{
  int lane = threadIdx.x & 63;
  int wave = threadIdx.x >> 6;
  int i0 = blockIdx.x * 128 + (wave >> 1) * 64;
  int j0 = blockIdx.y * 128 + (wave & 1) * 64;
  int lm = lane & 15, lk = lane >> 4;
  f32x4 acc[4][4];
#pragma unroll
  for (int r = 0; r < 4; ++r)
#pragma unroll
    for (int c = 0; c < 4; ++c) acc[r][c] = (f32x4){0.f, 0.f, 0.f, 0.f};
#pragma unroll
  for (int ks = 0; ks < 2; ++ks) {
    short8 Ah[4], Al[4], Bh[4], Bl[4];
#pragma unroll
    for (int t = 0; t < 4; ++t) {
      size_t ra = (size_t)(i0 + t * 16 + lm) * 64 + ks * 32 + lk * 8;
      size_t rb = (size_t)(j0 + t * 16 + lm) * 64 + ks * 32 + lk * 8;
      Ah[t] = *(const short8*)(hhi + ra);
      Al[t] = *(const short8*)(hlo + ra);
      Bh[t] = *(const short8*)(hhi + rb);
      Bl[t] = *(const short8*)(hlo + rb);
    }
#pragma unroll
    for (int r = 0; r < 4; ++r)
#pragma unroll
      for (int c = 0; c < 4; ++c) {
        acc[r][c] = __builtin_amdgcn_mfma_f32_16x16x32_bf16(Ah[r], Bh[c], acc[r][c], 0, 0, 0);
        acc[r][c] = __builtin_amdgcn_mfma_f32_16x16x32_bf16(Ah[r], Bl[c], acc[r][c], 0, 0, 0);
        acc[r][c] = __builtin_amdgcn_mfma_f32_16x16x32_bf16(Al[r], Bh[c], acc[r][c], 0, 0, 0);
      }
  }
#pragma unroll
  for (int r = 0; r < 4; ++r)
#pragma unroll
    for (int c = 0; c < 4; ++c) {
#pragma unroll
      for (int q = 0; q < 4; ++q) {
        float v = acc[r][c][q];
        float ex = __expf(-v);
        float s = 1.f / (1.f + ex);
        out[(size_t)(i0 + r * 16 + lk * 4 + q) * N_NODES + (j0 + c * 16 + lm)] = s;
      }
    }
}

// ---------------------------------------------------------------------------
extern "C" void kernel_launch(void* const* d_in, const int* in_sizes, int n_in,
                              void* d_out, int out_size, void* d_ws, size_t ws_size,
                              hipStream_t stream)
{
  const float* x     = (const float*)d_in[0];
  const float* W_s1  = (const float*)d_in[1];
  const float* b_s1  = (const float*)d_in[2];
  const float* W_g   = (const float*)d_in[3];
  const float* a_src = (const float*)d_in[4];
  const float* a_dst = (const float*)d_in[5];
  const float* b_g   = (const float*)d_in[6];
  const float* W_a1  = (const float*)d_in[7];
  const float* b_a1  = (const float*)d_in[8];
  const float* W_a2  = (const float*)d_in[9];
  const float* b_a2  = (const float*)d_in[10];
  const int*   ei    = (const int*)d_in[11];

  // ---- workspace carve-up
  float* ws   = (float*)d_ws;
  float* g    = ws;                              // 786432
  float* sc_s = g + (size_t)N_NODES * D_OUT;     // 12288
  float* sc_d = sc_s + N_NODES;                  // 12288
  float* part = sc_d + N_NODES;                  // 64*65536 = 4194304
  float* xt   = part + (size_t)64 * D_IN * D_EMB;// 65536
  float* xa   = xt + D_IN * D_EMB;               // 32768
  int* ip     = (int*)(xa + D_IN * D_OUT);
  int* flag   = ip;                              // 64
  int* deg    = ip + 64;                         // 12288
  int* rp     = deg + N_NODES;                   // 12352 (12289 used)
  int* cursor = rp + 12352;                      // 12288
  int* csr    = cursor + N_NODES;                // 393216
  ushort* up  = (ushort*)(csr + NEDGE);
  ushort* xhi  = up;                         up += (size_t)N_NODES * D_IN;
  ushort* xlo  = up;                         up += (size_t)N_NODES * D_IN;
  ushort* x1hi = up;                         up += (size_t)N_NODES * D_EMB;
  ushort* x1lo = up;                         up += (size_t)N_NODES * D_EMB;
  ushort* Ws1hi = up;                        up += (size_t)D_EMB * D_IN;
  ushort* Ws1lo = up;                        up += (size_t)D_EMB * D_IN;
  ushort* Wghi = up;                         up += (size_t)D_OUT * D_EMB;
  ushort* Wglo = up;                         up += (size_t)D_OUT * D_EMB;
  ushort* hhi = up;                          up += (size_t)N_NODES * D_OUT;
  ushort* hlo = up;                          up += (size_t)N_NODES * D_OUT;
  ushort* xahi = up;                         up += (size_t)D_IN * D_OUT;
  ushort* xalo = up;                         up += (size_t)D_IN * D_OUT;

  float* out_x = (float*)d_out;                       // 12288*512
  float* out_s = out_x + (size_t)N_NODES * D_IN;      // 12288*12288

  // ---- conversions (x streaming; W_s1+W_g merged)
  conv_hilo<<<(N_NODES * D_IN) / 1024, 256, 0, stream>>>(x, xhi, xlo);
  conv_w<<<72, 256, 0, stream>>>(W_s1, W_g, Ws1hi, Ws1lo, Wghi, Wglo);

  // ---- CSR build
  init_kernel<<<48, 256, 0, stream>>>(ei, flag, deg);
  edge_deg<<<NEDGE / 256, 256, 0, stream>>>(ei, flag, deg);
  scan_deg<<<1, 256, 0, stream>>>(deg, rp, cursor);
  edge_scatter<<<NEDGE / 256, 256, 0, stream>>>(ei, flag, cursor, csr);

  // ---- structure branch: x1 = relu(x@W_s1^T + b) -> bf16 hi/lo
  mfma_nt1<1><<<dim3(192, 2), 64, 0, stream>>>(
      xhi, xlo, Ws1hi, Ws1lo, b_s1, nullptr, x1hi, x1lo,
      D_IN, D_IN, D_IN, D_EMB);
  // g = x1 @ W_g^T (fp32 out)
  mfma_nt1<0><<<dim3(192, 1), 64, 0, stream>>>(
      x1hi, x1lo, Wghi, Wglo, nullptr, g, nullptr, nullptr,
      D_EMB, D_EMB, D_EMB, D_OUT);
  scores_kernel<<<N_NODES / 4, 256, 0, stream>>>(g, a_src, a_dst, sc_s, sc_d);
  gat_kernel<<<N_NODES / 4, 256, 0, stream>>>(rp, csr, sc_s, sc_d, g, b_g,
                                              hhi, hlo);

  // ---- attribute branch (fp32 split-K, reads x directly)
  xt_splitk<<<dim3(8, 64), 256, 0, stream>>>(x, W_a1, part);
  xt_ep<<<D_IN * D_EMB / 256, 256, 0, stream>>>(part, b_a1, xt);
  gemm_nt64<0><<<dim3(8, 1), 256, 0, stream>>>(xt, W_a2, b_a2, xa,
                                               D_IN, D_OUT, D_EMB, D_OUT);
  conv_hilo<<<(D_IN * D_OUT) / 1024, 256, 0, stream>>>(xa, xahi, xalo);

  // ---- outputs
  mfma_nt1<0><<<dim3(192, 8), 64, 0, stream>>>(
      hhi, hlo, xahi, xalo, nullptr, out_x, nullptr, nullptr,
      D_OUT, D_OUT, D_OUT, D_IN);
  sig_hht_mfma<<<dim3(96, 96), 256, 0, stream>>>(hhi, hlo, out_s);
}

// Round 7
// 897.600 us; speedup vs baseline: 1.0801x; 1.0190x over previous
//
#include <hip/hip_runtime.h>
#include <cstddef>
#include <cstdint>

#define N_NODES 12288
#define D_IN    512
#define D_EMB   128
#define D_OUT   64
#define NEDGE   393216

typedef __attribute__((ext_vector_type(8))) short short8;
typedef __attribute__((ext_vector_type(4))) float f32x4;

__device__ __forceinline__ ushort f2bf(float f) {
  uint32_t u = __float_as_uint(f);
  u += 0x7fffu + ((u >> 16) & 1u);
  return (ushort)(u >> 16);
}
__device__ __forceinline__ float bf2f(ushort h) {
  return __uint_as_float((uint32_t)h << 16);
}

// ---------------------------------------------------------------------------
// streaming fp32 -> bf16 hi/lo (n % 1024 == 0)
// ---------------------------------------------------------------------------
__global__ __launch_bounds__(256) void conv_hilo(const float* __restrict__ src,
    ushort* __restrict__ hi, ushort* __restrict__ lo)
{
  int idx = (blockIdx.x * 256 + threadIdx.x) * 4;
  float4 v = *(const float4*)(src + idx);
  const float* pv = &v.x;
  ushort4 h, l;
  ushort* ph = &h.x; ushort* pl = &l.x;
#pragma unroll
  for (int q = 0; q < 4; ++q) {
    ph[q] = f2bf(pv[q]);
    pl[q] = f2bf(pv[q] - bf2f(ph[q]));
  }
  *(ushort4*)(hi + idx) = h;
  *(ushort4*)(lo + idx) = l;
}

// merged W_s1 (65536) + W_g (8192) conversion: blocks [0,64) and [64,72)
__global__ __launch_bounds__(256) void conv_w(const float* __restrict__ Ws1,
    const float* __restrict__ Wg, ushort* __restrict__ s1h, ushort* __restrict__ s1l,
    ushort* __restrict__ wgh, ushort* __restrict__ wgl)
{
  int b = blockIdx.x;
  const float* src; ushort* hi; ushort* lo; int idx;
  if (b < 64) { src = Ws1; hi = s1h; lo = s1l; idx = (b * 256 + threadIdx.x) * 4; }
  else        { src = Wg;  hi = wgh; lo = wgl; idx = ((b - 64) * 256 + threadIdx.x) * 4; }
  float4 v = *(const float4*)(src + idx);
  const float* pv = &v.x;
  ushort4 h, l;
  ushort* ph = &h.x; ushort* pl = &l.x;
#pragma unroll
  for (int q = 0; q < 4; ++q) {
    ph[q] = f2bf(pv[q]);
    pl[q] = f2bf(pv[q] - bf2f(ph[q]));
  }
  *(ushort4*)(hi + idx) = h;
  *(ushort4*)(lo + idx) = l;
}

// ---------------------------------------------------------------------------
// CSR build
// ---------------------------------------------------------------------------
__global__ __launch_bounds__(256) void init_kernel(const int* __restrict__ ei,
    int* __restrict__ flag, int* __restrict__ deg)
{
  int idx = blockIdx.x * 256 + threadIdx.x;
  if (idx < N_NODES) deg[idx] = 0;
  if (idx == 0) {
    int ok = 1;
    for (int t = 0; t < 64; ++t) ok &= (ei[2 * t + 1] == 0);
    *flag = ok;  // 1 => data is int64, 0 => int32
  }
}

__global__ __launch_bounds__(256) void edge_deg(const int* __restrict__ ei,
    const int* __restrict__ flag, int* __restrict__ deg)
{
  int e = blockIdx.x * 256 + threadIdx.x;
  if (e >= NEDGE) return;
  int dst = (*flag) ? ei[2 * (NEDGE + e)] : ei[NEDGE + e];
  atomicAdd(&deg[dst], 1);
}

__global__ __launch_bounds__(256) void scan_deg(const int* __restrict__ deg,
    int* __restrict__ rp, int* __restrict__ cursor)
{
  __shared__ int sums[256];
  constexpr int C = N_NODES / 256;  // 48
  int t = threadIdx.x;
  int base = t * C;
  int local[C];
  int s = 0;
  for (int i = 0; i < C; ++i) { local[i] = deg[base + i]; s += local[i]; }
  sums[t] = s;
  __syncthreads();
  for (int off = 1; off < 256; off <<= 1) {
    int v = (t >= off) ? sums[t - off] : 0;
    __syncthreads();
    sums[t] += v;
    __syncthreads();
  }
  int prefix = (t == 0) ? 0 : sums[t - 1];
  for (int i = 0; i < C; ++i) {
    rp[base + i] = prefix;
    cursor[base + i] = prefix;
    prefix += local[i];
  }
  if (t == 255) rp[N_NODES] = prefix;
}

__global__ __launch_bounds__(256) void edge_scatter(const int* __restrict__ ei,
    const int* __restrict__ flag, int* __restrict__ cursor, int* __restrict__ csr)
{
  int e = blockIdx.x * 256 + threadIdx.x;
  if (e >= NEDGE) return;
  int is64 = *flag;
  int src = is64 ? ei[2 * e] : ei[e];
  int dst = is64 ? ei[2 * (NEDGE + e)] : ei[NEDGE + e];
  int p = atomicAdd(&cursor[dst], 1);
  csr[p] = src;
}

// ---------------------------------------------------------------------------
// Single-wave NT MFMA GEMM, 3-term bf16 hi/lo split (lo*lo dropped).
// One 64x64 wave tile per 64-thread block; grid (M/64, N/64).
// MODE 0: fp32 out. MODE 1: +bias, relu, bf16 hi/lo out.
// Layouts (m89/m91, validated R2/R4/R5):
//   A/B frag: [m = lane&15][k = (lane>>4)*8 + j]
//   C/D:      col = lane&15, row = (lane>>4)*4 + reg
// ---------------------------------------------------------------------------
template<int MODE>
__global__ __launch_bounds__(64) void mfma_nt1(
    const ushort* __restrict__ Ahi, const ushort* __restrict__ Alo,
    const ushort* __restrict__ Bhi, const ushort* __restrict__ Blo,
    const float* __restrict__ bias,
    float* __restrict__ Cf, ushort* __restrict__ Chi, ushort* __restrict__ Clo,
    int lda, int ldb, int K, int ldc)
{
  int lane = threadIdx.x;
  int i0 = blockIdx.x * 64;
  int j0 = blockIdx.y * 64;
  int lm = lane & 15, lk = lane >> 4;
  f32x4 acc[4][4];
#pragma unroll
  for (int r = 0; r < 4; ++r)
#pragma unroll
    for (int c = 0; c < 4; ++c) acc[r][c] = (f32x4){0.f, 0.f, 0.f, 0.f};

  for (int k0 = 0; k0 < K; k0 += 32) {
    int kk = k0 + lk * 8;
    short8 Ah[4], Al[4], Bh[4], Bl[4];
#pragma unroll
    for (int t = 0; t < 4; ++t) {
      size_t ra = (size_t)(i0 + t * 16 + lm) * lda + kk;
      size_t rb = (size_t)(j0 + t * 16 + lm) * ldb + kk;
      Ah[t] = *(const short8*)(Ahi + ra);
      Al[t] = *(const short8*)(Alo + ra);
      Bh[t] = *(const short8*)(Bhi + rb);
      Bl[t] = *(const short8*)(Blo + rb);
    }
#pragma unroll
    for (int r = 0; r < 4; ++r)
#pragma unroll
      for (int c = 0; c < 4; ++c) {
        acc[r][c] = __builtin_amdgcn_mfma_f32_16x16x32_bf16(Ah[r], Bh[c], acc[r][c], 0, 0, 0);
        acc[r][c] = __builtin_amdgcn_mfma_f32_16x16x32_bf16(Ah[r], Bl[c], acc[r][c], 0, 0, 0);
        acc[r][c] = __builtin_amdgcn_mfma_f32_16x16x32_bf16(Al[r], Bh[c], acc[r][c], 0, 0, 0);
      }
  }
#pragma unroll
  for (int r = 0; r < 4; ++r)
#pragma unroll
    for (int c = 0; c < 4; ++c) {
      int col = j0 + c * 16 + lm;
#pragma unroll
      for (int q = 0; q < 4; ++q) {
        int row = i0 + r * 16 + lk * 4 + q;
        float v = acc[r][c][q];
        if (MODE == 0) {
          Cf[(size_t)row * ldc + col] = v;
        } else {
          v += bias[col];
          v = fmaxf(v, 0.f);
          ushort hb = f2bf(v);
          Chi[(size_t)row * ldc + col] = hb;
          Clo[(size_t)row * ldc + col] = f2bf(v - bf2f(hb));
        }
      }
    }
}

// ---------------------------------------------------------------------------
// small fp32 NT GEMM (xa: 512x64x128)
// ---------------------------------------------------------------------------
template<int ACT>
__global__ __launch_bounds__(256) void gemm_nt64(const float* __restrict__ A,
    const float* __restrict__ B, const float* __restrict__ bias,
    float* __restrict__ C, int M, int N, int K, int ldc)
{
  __shared__ float As[32][64];
  __shared__ float Bs[32][64];
  int m0 = blockIdx.x * 64, n0 = blockIdx.y * 64;
  int tid = threadIdx.x;
  int tx = tid & 15, ty = tid >> 4;
  float acc[4][4] = {};
  for (int k0 = 0; k0 < K; k0 += 32) {
#pragma unroll
    for (int p = 0; p < 2; ++p) {
      int idx = tid + p * 256;
      int row = idx >> 3;
      int kq  = idx & 7;
      float4 va = *(const float4*)(A + (size_t)(m0 + row) * K + k0 + kq * 4);
      As[kq*4+0][row] = va.x; As[kq*4+1][row] = va.y;
      As[kq*4+2][row] = va.z; As[kq*4+3][row] = va.w;
      float4 vb = *(const float4*)(B + (size_t)(n0 + row) * K + k0 + kq * 4);
      Bs[kq*4+0][row] = vb.x; Bs[kq*4+1][row] = vb.y;
      Bs[kq*4+2][row] = vb.z; Bs[kq*4+3][row] = vb.w;
    }
    __syncthreads();
#pragma unroll
    for (int k = 0; k < 32; ++k) {
      float a[4], b[4];
      *(float4*)a = *(const float4*)&As[k][ty * 4];
      *(float4*)b = *(const float4*)&Bs[k][tx * 4];
#pragma unroll
      for (int r = 0; r < 4; ++r)
#pragma unroll
        for (int c = 0; c < 4; ++c)
          acc[r][c] = fmaf(a[r], b[c], acc[r][c]);
    }
    __syncthreads();
  }
#pragma unroll
  for (int r = 0; r < 4; ++r) {
    int m = m0 + ty * 4 + r;
    float4 o;
    float* po = &o.x;
#pragma unroll
    for (int c = 0; c < 4; ++c) {
      float v = acc[r][c];
      if (bias) v += bias[n0 + tx * 4 + c];
      if (ACT) v = fmaxf(v, 0.f);
      po[c] = v;
    }
    *(float4*)(C + (size_t)m * ldc + n0 + tx * 4) = o;
  }
}

// per-node attention scores
__global__ __launch_bounds__(256) void scores_kernel(const float* __restrict__ g,
    const float* __restrict__ a_src, const float* __restrict__ a_dst,
    float* __restrict__ sc_s, float* __restrict__ sc_d)
{
  int lane = threadIdx.x & 63;
  int i = blockIdx.x * 4 + (threadIdx.x >> 6);
  float gv = g[(size_t)i * 64 + lane];
  float vs = gv * a_src[lane];
  float vd = gv * a_dst[lane];
#pragma unroll
  for (int off = 32; off; off >>= 1) {
    vs += __shfl_xor(vs, off);
    vd += __shfl_xor(vd, off);
  }
  if (lane == 0) { sc_s[i] = vs; sc_d[i] = vd; }
}

// one wave per destination node; softmax weights cached in per-wave LDS
#define WCAP 192
__global__ __launch_bounds__(256) void gat_kernel(const int* __restrict__ rp,
    const int* __restrict__ csr, const float* __restrict__ sc_s,
    const float* __restrict__ sc_d, const float* __restrict__ g,
    const float* __restrict__ b_g,
    ushort* __restrict__ hhi, ushort* __restrict__ hlo)
{
  __shared__ float wbuf[4][WCAP];
  __shared__ int   sbuf[4][WCAP];
  int lane = threadIdx.x & 63;
  int w = threadIdx.x >> 6;
  int i = blockIdx.x * 4 + w;
  int beg = rp[i], end = rp[i + 1];
  int deg = end - beg;
  float scd = sc_d[i];
  float mymax = -3.4e38f;
  for (int j = lane; j <= deg; j += 64) {
    int s = (j < deg) ? csr[beg + j] : i;
    float e = sc_s[s] + scd;
    e = (e > 0.f) ? e : 0.2f * e;
    mymax = fmaxf(mymax, e);
    if (j < WCAP) sbuf[w][j] = s;
  }
#pragma unroll
  for (int off = 32; off; off >>= 1) mymax = fmaxf(mymax, __shfl_xor(mymax, off));
  float sum = 0.f;
  for (int j = lane; j <= deg; j += 64) {
    int s = (j < WCAP) ? sbuf[w][j] : ((j < deg) ? csr[beg + j] : i);
    float e = sc_s[s] + scd;
    e = (e > 0.f) ? e : 0.2f * e;
    float ex = __expf(e - mymax);
    sum += ex;
    if (j < WCAP) wbuf[w][j] = ex;
  }
#pragma unroll
  for (int off = 32; off; off >>= 1) sum += __shfl_xor(sum, off);
  float inv = 1.f / sum;
  float acc = 0.f;   // lane == feature
  for (int j = 0; j <= deg; ++j) {
    int s; float ex;
    if (j < WCAP) { s = sbuf[w][j]; ex = wbuf[w][j]; }
    else {
      s = (j < deg) ? csr[beg + j] : i;
      float e = sc_s[s] + scd;
      e = (e > 0.f) ? e : 0.2f * e;
      ex = __expf(e - mymax);
    }
    acc = fmaf(ex * inv, g[(size_t)s * 64 + lane], acc);
  }
  float val = acc + b_g[lane];
  size_t o = (size_t)i * 64 + lane;
  ushort hi = f2bf(val);
  hhi[o] = hi;
  hlo[o] = f2bf(val - bf2f(hi));
}

// ---------------------------------------------------------------------------
// xt pre-activation partials: part[chunk][c][j] over 192-row chunks
// grid (8 c-tiles, 64 chunks), 256 thr, thread tile 4c x 8j. No atomics.
// ---------------------------------------------------------------------------
__global__ __launch_bounds__(256) void xt_splitk(const float* __restrict__ x,
    const float* __restrict__ Wa1, float* __restrict__ part)
{
  __shared__ float Xs[32][64];    // [i][c]
  __shared__ float Ws[32][128];   // [i][j]
  int c0 = blockIdx.x * 64;
  int i0 = blockIdx.y * 192;
  float* pout = part + (size_t)blockIdx.y * (D_IN * D_EMB);
  int tid = threadIdx.x;
  int txc = tid & 15, txj = tid >> 4;
  float acc[4][8] = {};
  for (int ib = 0; ib < 192; ib += 32) {
#pragma unroll
    for (int p = 0; p < 2; ++p) {    // Xs: 32x64 = 512 float4
      int idx = tid + p * 256;
      int row = idx >> 4, q = idx & 15;
      *(float4*)&Xs[row][q * 4] =
          *(const float4*)(x + (size_t)(i0 + ib + row) * D_IN + c0 + q * 4);
    }
#pragma unroll
    for (int p = 0; p < 4; ++p) {    // Ws: 128 rows x 8 float4 (transposed store)
      int idx = tid + p * 256;
      int j = idx >> 3, q = idx & 7;
      float4 v = *(const float4*)(Wa1 + (size_t)j * N_NODES + i0 + ib + q * 4);
      Ws[q*4+0][j] = v.x; Ws[q*4+1][j] = v.y;
      Ws[q*4+2][j] = v.z; Ws[q*4+3][j] = v.w;
    }
    __syncthreads();
#pragma unroll
    for (int ii = 0; ii < 32; ++ii) {
      float a[4], b[8];
      *(float4*)a = *(const float4*)&Xs[ii][txc * 4];
      *(float4*)&b[0] = *(const float4*)&Ws[ii][txj * 8];
      *(float4*)&b[4] = *(const float4*)&Ws[ii][txj * 8 + 4];
#pragma unroll
      for (int r = 0; r < 4; ++r)
#pragma unroll
        for (int c = 0; c < 8; ++c)
          acc[r][c] = fmaf(a[r], b[c], acc[r][c]);
    }
    __syncthreads();
  }
#pragma unroll
  for (int r = 0; r < 4; ++r) {
    float4 o0, o1;
    o0.x = acc[r][0]; o0.y = acc[r][1]; o0.z = acc[r][2]; o0.w = acc[r][3];
    o1.x = acc[r][4]; o1.y = acc[r][5]; o1.z = acc[r][6]; o1.w = acc[r][7];
    size_t off = (size_t)(c0 + txc * 4 + r) * D_EMB + txj * 8;
    *(float4*)&pout[off] = o0;
    *(float4*)&pout[off + 4] = o1;
  }
}

// reduce 64 partial chunks, add bias, relu
__global__ __launch_bounds__(256) void xt_ep(const float* __restrict__ part,
    const float* __restrict__ b_a1, float* __restrict__ xt)
{
  int idx = blockIdx.x * 256 + threadIdx.x;  // 65536
  float v = b_a1[idx & 127];
#pragma unroll 8
  for (int c = 0; c < 64; ++c) v += part[(size_t)c * (D_IN * D_EMB) + idx];
  xt[idx] = fmaxf(v, 0.f);
}

// ---------------------------------------------------------------------------
// s_ = sigmoid(h @ h^T), bf16 MFMA 3-term, 128x128 per block, no LDS.
// Sigmoid via v_exp + v_rcp (validated in R2).
// ---------------------------------------------------------------------------
__global__ __launch_bounds__(256) void sig_hht_mfma(const ushort* __restrict__ hhi,
    const ushort* __restrict__ hlo, float* __restrict__ out)
{
  int lane = threadIdx.x & 63;
  int wave = threadIdx.x >> 6;
  int i0 = blockIdx.x * 128 + (wave >> 1) * 64;
  int j0 = blockIdx.y * 128 + (wave & 1) * 64;
  int lm = lane & 15, lk = lane >> 4;
  f32x4 acc[4][4];
#pragma unroll
  for (int r = 0; r < 4; ++r)
#pragma unroll
    for (int c = 0; c < 4; ++c) acc[r][c] = (f32x4){0.f, 0.f, 0.f, 0.f};
#pragma unroll
  for (int ks = 0; ks < 2; ++ks) {
    short8 Ah[4], Al[4], Bh[4], Bl[4];
#pragma unroll
    for (int t = 0; t < 4; ++t) {
      size_t ra = (size_t)(i0 + t * 16 + lm) * 64 + ks * 32 + lk * 8;
      size_t rb = (size_t)(j0 + t * 16 + lm) * 64 + ks * 32 + lk * 8;
      Ah[t] = *(const short8*)(hhi + ra);
      Al[t] = *(const short8*)(hlo + ra);
      Bh[t] = *(const short8*)(hhi + rb);
      Bl[t] = *(const short8*)(hlo + rb);
    }
#pragma unroll
    for (int r = 0; r < 4; ++r)
#pragma unroll
      for (int c = 0; c < 4; ++c) {
        acc[r][c] = __builtin_amdgcn_mfma_f32_16x16x32_bf16(Ah[r], Bh[c], acc[r][c], 0, 0, 0);
        acc[r][c] = __builtin_amdgcn_mfma_f32_16x16x32_bf16(Ah[r], Bl[c], acc[r][c], 0, 0, 0);
        acc[r][c] = __builtin_amdgcn_mfma_f32_16x16x32_bf16(Al[r], Bh[c], acc[r][c], 0, 0, 0);
      }
  }
#pragma unroll
  for (int r = 0; r < 4; ++r)
#pragma unroll
    for (int c = 0; c < 4; ++c) {
#pragma unroll
      for (int q = 0; q < 4; ++q) {
        float v = acc[r][c][q];
        float ex = __expf(-v);
#if __has_builtin(__builtin_amdgcn_rcpf)
        float s = __builtin_amdgcn_rcpf(1.f + ex);
#else
        float s = 1.f / (1.f + ex);
#endif
        out[(size_t)(i0 + r * 16 + lk * 4 + q) * N_NODES + (j0 + c * 16 + lm)] = s;
      }
    }
}

// ---------------------------------------------------------------------------
extern "C" void kernel_launch(void* const* d_in, const int* in_sizes, int n_in,
                              void* d_out, int out_size, void* d_ws, size_t ws_size,
                              hipStream_t stream)
{
  const float* x     = (const float*)d_in[0];
  const float* W_s1  = (const float*)d_in[1];
  const float* b_s1  = (const float*)d_in[2];
  const float* W_g   = (const float*)d_in[3];
  const float* a_src = (const float*)d_in[4];
  const float* a_dst = (const float*)d_in[5];
  const float* b_g   = (const float*)d_in[6];
  const float* W_a1  = (const float*)d_in[7];
  const float* b_a1  = (const float*)d_in[8];
  const float* W_a2  = (const float*)d_in[9];
  const float* b_a2  = (const float*)d_in[10];
  const int*   ei    = (const int*)d_in[11];

  // ---- workspace carve-up
  float* ws   = (float*)d_ws;
  float* g    = ws;                              // 786432
  float* sc_s = g + (size_t)N_NODES * D_OUT;     // 12288
  float* sc_d = sc_s + N_NODES;                  // 12288
  float* part = sc_d + N_NODES;                  // 64*65536 = 4194304
  float* xt   = part + (size_t)64 * D_IN * D_EMB;// 65536
  float* xa   = xt + D_IN * D_EMB;               // 32768
  int* ip     = (int*)(xa + D_IN * D_OUT);
  int* flag   = ip;                              // 64
  int* deg    = ip + 64;                         // 12288
  int* rp     = deg + N_NODES;                   // 12352 (12289 used)
  int* cursor = rp + 12352;                      // 12288
  int* csr    = cursor + N_NODES;                // 393216
  ushort* up  = (ushort*)(csr + NEDGE);
  ushort* xhi  = up;                         up += (size_t)N_NODES * D_IN;
  ushort* xlo  = up;                         up += (size_t)N_NODES * D_IN;
  ushort* x1hi = up;                         up += (size_t)N_NODES * D_EMB;
  ushort* x1lo = up;                         up += (size_t)N_NODES * D_EMB;
  ushort* Ws1hi = up;                        up += (size_t)D_EMB * D_IN;
  ushort* Ws1lo = up;                        up += (size_t)D_EMB * D_IN;
  ushort* Wghi = up;                         up += (size_t)D_OUT * D_EMB;
  ushort* Wglo = up;                         up += (size_t)D_OUT * D_EMB;
  ushort* hhi = up;                          up += (size_t)N_NODES * D_OUT;
  ushort* hlo = up;                          up += (size_t)N_NODES * D_OUT;
  ushort* xahi = up;                         up += (size_t)D_IN * D_OUT;
  ushort* xalo = up;                         up += (size_t)D_IN * D_OUT;

  float* out_x = (float*)d_out;                       // 12288*512
  float* out_s = out_x + (size_t)N_NODES * D_IN;      // 12288*12288

  // ---- conversions (x streaming; W_s1+W_g merged)
  conv_hilo<<<(N_NODES * D_IN) / 1024, 256, 0, stream>>>(x, xhi, xlo);
  conv_w<<<72, 256, 0, stream>>>(W_s1, W_g, Ws1hi, Ws1lo, Wghi, Wglo);

  // ---- CSR build
  init_kernel<<<48, 256, 0, stream>>>(ei, flag, deg);
  edge_deg<<<NEDGE / 256, 256, 0, stream>>>(ei, flag, deg);
  scan_deg<<<1, 256, 0, stream>>>(deg, rp, cursor);
  edge_scatter<<<NEDGE / 256, 256, 0, stream>>>(ei, flag, cursor, csr);

  // ---- structure branch: x1 = relu(x@W_s1^T + b) -> bf16 hi/lo
  mfma_nt1<1><<<dim3(192, 2), 64, 0, stream>>>(
      xhi, xlo, Ws1hi, Ws1lo, b_s1, nullptr, x1hi, x1lo,
      D_IN, D_IN, D_IN, D_EMB);
  // g = x1 @ W_g^T (fp32 out)
  mfma_nt1<0><<<dim3(192, 1), 64, 0, stream>>>(
      x1hi, x1lo, Wghi, Wglo, nullptr, g, nullptr, nullptr,
      D_EMB, D_EMB, D_EMB, D_OUT);
  scores_kernel<<<N_NODES / 4, 256, 0, stream>>>(g, a_src, a_dst, sc_s, sc_d);
  gat_kernel<<<N_NODES / 4, 256, 0, stream>>>(rp, csr, sc_s, sc_d, g, b_g,
                                              hhi, hlo);

  // ---- attribute branch (fp32 split-K, reads x directly)
  xt_splitk<<<dim3(8, 64), 256, 0, stream>>>(x, W_a1, part);
  xt_ep<<<D_IN * D_EMB / 256, 256, 0, stream>>>(part, b_a1, xt);
  gemm_nt64<0><<<dim3(8, 1), 256, 0, stream>>>(xt, W_a2, b_a2, xa,
                                               D_IN, D_OUT, D_EMB, D_OUT);
  conv_hilo<<<(D_IN * D_OUT) / 1024, 256, 0, stream>>>(xa, xahi, xalo);

  // ---- outputs
  mfma_nt1<0><<<dim3(192, 8), 64, 0, stream>>>(
      hhi, hlo, xahi, xalo, nullptr, out_x, nullptr, nullptr,
      D_OUT, D_OUT, D_OUT, D_IN);
  sig_hht_mfma<<<dim3(96, 96), 256, 0, stream>>>(hhi, hlo, out_s);
}